// Round 3
// baseline (196.580 us; speedup 1.0000x reference)
//
#include <hip/hip_runtime.h>
#include <hip/hip_cooperative_groups.h>

// LTPE: y(p) = x(p) - sum_j w_j * x(p + off_j), zero-padded borders,
// then instance-norm over HxW per image: (y - mean) * rsqrt(var + 4e-5).
// (The reference's out = 0.5*y + 0.5; instance norm is affine-invariant,
//  with eps folding 1e-5 -> 4e-5.)
//
// Single cooperative kernel: stats phase -> grid.sync() -> normalize phase.
// Kills the inter-kernel pipeline drain and keeps x L3-resident for phase 2.

#define HH 1024
#define WW 1024
#define NIMG 32
#define NBLK 32                  // blocks per image
#define ROWS_PER_BLK (HH / NBLK) // 32
#define TPB 256                  // = WW/4 float4 columns per row

typedef float vfloat4 __attribute__((ext_vector_type(4)));

namespace cg = cooperative_groups;

// weights: j=0..7 -> 2^j/255, offsets (dy,dx):
// j0 (0,-1), j1 (1,-1), j2 (1,0), j3 (1,1), j4 (0,1), j5 (-1,1), j6 (-1,0), j7 (-1,-1)
__device__ __forceinline__ void compute_y(const float* up, const float* mid,
                                          const float* dn, float* y) {
    const float w0 = 1.f / 255.f,  w1 = 2.f / 255.f,  w2 = 4.f / 255.f,
                w3 = 8.f / 255.f,  w4 = 16.f / 255.f, w5 = 32.f / 255.f,
                w6 = 64.f / 255.f, w7 = 128.f / 255.f;
#pragma unroll
    for (int k = 0; k < 4; ++k) {
        float s = w0 * mid[k] + w4 * mid[k + 2]
                + w1 * dn[k]  + w2 * dn[k + 1] + w3 * dn[k + 2]
                + w7 * up[k]  + w6 * up[k + 1] + w5 * up[k + 2];
        y[k] = mid[k + 1] - s;
    }
}

// buf[0]=left halo, buf[1..4]=vfloat4, buf[5]=right halo
__device__ __forceinline__ void load_row(const float* __restrict__ row, int c,
                                         float* buf) {
    const vfloat4 v = reinterpret_cast<const vfloat4*>(row)[c];
    buf[0] = (c > 0) ? row[4 * c - 1] : 0.f;
    buf[1] = v.x; buf[2] = v.y; buf[3] = v.z; buf[4] = v.w;
    buf[5] = (c < TPB - 1) ? row[4 * c + 4] : 0.f;
}

__device__ __forceinline__ void zero_row(float* buf) {
#pragma unroll
    for (int k = 0; k < 6; ++k) buf[k] = 0.f;
}

__global__ __launch_bounds__(TPB) void ltpe_fused(const float* __restrict__ x,
                                                  float* __restrict__ partials,
                                                  float* __restrict__ out) {
    const int img = blockIdx.x / NBLK;
    const int blk = blockIdx.x % NBLK;
    const int c = threadIdx.x;
    const float* base = x + (size_t)img * HH * WW;
    const int r0 = blk * ROWS_PER_BLK;

    // ---------------- phase 1: partial sums of y and y^2 ----------------
    {
        float up[6], mid[6], dn[6];
        if (r0 > 0) load_row(base + (size_t)(r0 - 1) * WW, c, up); else zero_row(up);
        load_row(base + (size_t)r0 * WW, c, mid);

        float s = 0.f, ss = 0.f;
        for (int i = 0; i < ROWS_PER_BLK; ++i) {
            const int r = r0 + i;
            if (r + 1 < HH) load_row(base + (size_t)(r + 1) * WW, c, dn);
            else zero_row(dn);
            float y[4];
            compute_y(up, mid, dn, y);
#pragma unroll
            for (int k = 0; k < 4; ++k) { s += y[k]; ss = fmaf(y[k], y[k], ss); }
#pragma unroll
            for (int k = 0; k < 6; ++k) { up[k] = mid[k]; mid[k] = dn[k]; }
        }

#pragma unroll
        for (int off = 32; off > 0; off >>= 1) {
            s += __shfl_down(s, off);
            ss += __shfl_down(ss, off);
        }
        __shared__ float sh[8];
        const int wave = threadIdx.x >> 6;
        const int lane = threadIdx.x & 63;
        if (lane == 0) { sh[wave] = s; sh[4 + wave] = ss; }
        __syncthreads();
        if (threadIdx.x == 0) {
            partials[img * NBLK + blk] = sh[0] + sh[1] + sh[2] + sh[3];
            partials[NIMG * NBLK + img * NBLK + blk] = sh[4] + sh[5] + sh[6] + sh[7];
        }
    }

    __threadfence();
    cg::this_grid().sync();

    // ------------- phase 2: redundant final reduce + normalize -------------
    __shared__ float sh_stats[2];
    if (threadIdx.x < 64) {
        const int lane = threadIdx.x;
        double S = 0.0, SS = 0.0;
        if (lane < NBLK) {
            S = (double)partials[img * NBLK + lane];
            SS = (double)partials[NIMG * NBLK + img * NBLK + lane];
        }
#pragma unroll
        for (int off = 32; off > 0; off >>= 1) {
            S += __shfl_down(S, off);
            SS += __shfl_down(SS, off);
        }
        if (lane == 0) {
            const double N = (double)HH * (double)WW;
            const double mean = S / N;
            const double var = SS / N - mean * mean;
            sh_stats[0] = (float)mean;
            sh_stats[1] = (float)(1.0 / sqrt(var + 4e-5)); // 4*eps folds the 0.5
        }
    }
    __syncthreads();
    const float mean = sh_stats[0];
    const float scale = sh_stats[1];

    float* obase = out + (size_t)img * HH * WW;
    float up[6], mid[6], dn[6];
    if (r0 > 0) load_row(base + (size_t)(r0 - 1) * WW, c, up); else zero_row(up);
    load_row(base + (size_t)r0 * WW, c, mid);

    for (int i = 0; i < ROWS_PER_BLK; ++i) {
        const int r = r0 + i;
        if (r + 1 < HH) load_row(base + (size_t)(r + 1) * WW, c, dn);
        else zero_row(dn);
        float y[4];
        compute_y(up, mid, dn, y);
        vfloat4 o;
        o.x = (y[0] - mean) * scale;
        o.y = (y[1] - mean) * scale;
        o.z = (y[2] - mean) * scale;
        o.w = (y[3] - mean) * scale;
        // Non-temporal: don't let the 128 MB output stream evict x from L3.
        vfloat4* op = reinterpret_cast<vfloat4*>(obase + (size_t)r * WW) + c;
        __builtin_nontemporal_store(o, op);
#pragma unroll
        for (int k = 0; k < 6; ++k) { up[k] = mid[k]; mid[k] = dn[k]; }
    }
}

extern "C" void kernel_launch(void* const* d_in, const int* in_sizes, int n_in,
                              void* d_out, int out_size, void* d_ws, size_t ws_size,
                              hipStream_t stream) {
    const float* x = (const float*)d_in[0];
    float* out = (float*)d_out;
    float* partials = (float*)d_ws; // [NIMG*NBLK sums][NIMG*NBLK sumsqs]

    void* args[] = {(void*)&x, (void*)&partials, (void*)&out};
    hipLaunchCooperativeKernel((const void*)ltpe_fused, dim3(NIMG * NBLK),
                               dim3(TPB), args, 0, stream);
}

// Round 5
// 170.850 us; speedup vs baseline: 1.1506x; 1.1506x over previous
//
#include <hip/hip_runtime.h>

// LTPE: y(p) = x(p) - sum_j w_j * x(p + off_j), zero-padded borders,
// then instance-norm over HxW per image: (y - mean) * rsqrt(var + 4e-5).
// (The reference's out = 0.5*y + 0.5; instance norm is affine-invariant,
//  with eps folding 1e-5 -> 4e-5.)
//
// Single fused dispatch with PER-IMAGE completion counters instead of a
// grid-wide cooperative barrier (round-3 showed cg::grid().sync() costs
// ~170us here). Each image's 32 blocks: stats -> release-add counter ->
// spin until ==32 -> redundant 32-wide reduce -> normalize own rows.

#define HH 1024
#define WW 1024
#define NIMG 32
#define NBLK 32                  // blocks per image
#define ROWS_PER_BLK (HH / NBLK) // 32
#define TPB 256                  // = WW/4 float4 columns per row

typedef float vfloat4 __attribute__((ext_vector_type(4)));

// weights: j=0..7 -> 2^j/255, offsets (dy,dx):
// j0 (0,-1), j1 (1,-1), j2 (1,0), j3 (1,1), j4 (0,1), j5 (-1,1), j6 (-1,0), j7 (-1,-1)
__device__ __forceinline__ void compute_y(const float* up, const float* mid,
                                          const float* dn, float* y) {
    const float w0 = 1.f / 255.f,  w1 = 2.f / 255.f,  w2 = 4.f / 255.f,
                w3 = 8.f / 255.f,  w4 = 16.f / 255.f, w5 = 32.f / 255.f,
                w6 = 64.f / 255.f, w7 = 128.f / 255.f;
#pragma unroll
    for (int k = 0; k < 4; ++k) {
        float s = w0 * mid[k] + w4 * mid[k + 2]
                + w1 * dn[k]  + w2 * dn[k + 1] + w3 * dn[k + 2]
                + w7 * up[k]  + w6 * up[k + 1] + w5 * up[k + 2];
        y[k] = mid[k + 1] - s;
    }
}

// buf[0]=left halo, buf[1..4]=vfloat4, buf[5]=right halo
__device__ __forceinline__ void load_row(const float* __restrict__ row, int c,
                                         float* buf) {
    const vfloat4 v = reinterpret_cast<const vfloat4*>(row)[c];
    buf[0] = (c > 0) ? row[4 * c - 1] : 0.f;
    buf[1] = v.x; buf[2] = v.y; buf[3] = v.z; buf[4] = v.w;
    buf[5] = (c < TPB - 1) ? row[4 * c + 4] : 0.f;
}

__device__ __forceinline__ void zero_row(float* buf) {
#pragma unroll
    for (int k = 0; k < 6; ++k) buf[k] = 0.f;
}

__global__ __launch_bounds__(NIMG) void ltpe_zero_counts(int* __restrict__ count) {
    count[threadIdx.x] = 0;
}

__global__ __launch_bounds__(TPB, 4) void ltpe_onepass(const float* __restrict__ x,
                                                       float* __restrict__ partials,
                                                       int* __restrict__ count,
                                                       float* __restrict__ out) {
    const int img = blockIdx.x / NBLK;
    const int blk = blockIdx.x % NBLK;
    const int c = threadIdx.x;
    const float* base = x + (size_t)img * HH * WW;
    const int r0 = blk * ROWS_PER_BLK;

    // ---------------- phase 1: partial sums of y and y^2 ----------------
    {
        float up[6], mid[6], dn[6];
        if (r0 > 0) load_row(base + (size_t)(r0 - 1) * WW, c, up); else zero_row(up);
        load_row(base + (size_t)r0 * WW, c, mid);

        float s = 0.f, ss = 0.f;
        for (int i = 0; i < ROWS_PER_BLK; ++i) {
            const int r = r0 + i;
            if (r + 1 < HH) load_row(base + (size_t)(r + 1) * WW, c, dn);
            else zero_row(dn);
            float y[4];
            compute_y(up, mid, dn, y);
#pragma unroll
            for (int k = 0; k < 4; ++k) { s += y[k]; ss = fmaf(y[k], y[k], ss); }
#pragma unroll
            for (int k = 0; k < 6; ++k) { up[k] = mid[k]; mid[k] = dn[k]; }
        }

#pragma unroll
        for (int off = 32; off > 0; off >>= 1) {
            s += __shfl_down(s, off);
            ss += __shfl_down(ss, off);
        }
        __shared__ float sh[8];
        const int wave = threadIdx.x >> 6;
        const int lane = threadIdx.x & 63;
        if (lane == 0) { sh[wave] = s; sh[4 + wave] = ss; }
        __syncthreads();
        if (threadIdx.x == 0) {
            partials[img * NBLK + blk] = sh[0] + sh[1] + sh[2] + sh[3];
            partials[NIMG * NBLK + img * NBLK + blk] = sh[4] + sh[5] + sh[6] + sh[7];
            // release: make partials visible device-wide, then signal
            __hip_atomic_fetch_add(&count[img], 1, __ATOMIC_RELEASE,
                                   __HIP_MEMORY_SCOPE_AGENT);
        }
    }

    // ------- wait for this image's 32 blocks (bounded, per-image skew) -------
    if (threadIdx.x == 0) {
        while (__hip_atomic_load(&count[img], __ATOMIC_ACQUIRE,
                                 __HIP_MEMORY_SCOPE_AGENT) < NBLK) {
            __builtin_amdgcn_s_sleep(8);
        }
    }
    __syncthreads();
    __builtin_amdgcn_fence(__ATOMIC_ACQUIRE, "agent");

    // ------------- redundant per-block final reduce (one wave) -------------
    __shared__ float sh_stats[2];
    if (threadIdx.x < 64) {
        const int lane = threadIdx.x;
        double S = 0.0, SS = 0.0;
        if (lane < NBLK) {
            S = (double)partials[img * NBLK + lane];
            SS = (double)partials[NIMG * NBLK + img * NBLK + lane];
        }
#pragma unroll
        for (int off = 32; off > 0; off >>= 1) {
            S += __shfl_down(S, off);
            SS += __shfl_down(SS, off);
        }
        if (lane == 0) {
            const double N = (double)HH * (double)WW;
            const double mean = S / N;
            const double var = SS / N - mean * mean;
            sh_stats[0] = (float)mean;
            sh_stats[1] = (float)(1.0 / sqrt(var + 4e-5)); // 4*eps folds the 0.5
        }
    }
    __syncthreads();
    const float mean = sh_stats[0];
    const float scale = sh_stats[1];

    // ---------------- phase 2: normalize own rows (cache-warm) ----------------
    float* obase = out + (size_t)img * HH * WW;
    float up[6], mid[6], dn[6];
    if (r0 > 0) load_row(base + (size_t)(r0 - 1) * WW, c, up); else zero_row(up);
    load_row(base + (size_t)r0 * WW, c, mid);

    for (int i = 0; i < ROWS_PER_BLK; ++i) {
        const int r = r0 + i;
        if (r + 1 < HH) load_row(base + (size_t)(r + 1) * WW, c, dn);
        else zero_row(dn);
        float y[4];
        compute_y(up, mid, dn, y);
        vfloat4 o;
        o.x = (y[0] - mean) * scale;
        o.y = (y[1] - mean) * scale;
        o.z = (y[2] - mean) * scale;
        o.w = (y[3] - mean) * scale;
        // Non-temporal: don't let the 128 MB output stream evict x from L3.
        vfloat4* op = reinterpret_cast<vfloat4*>(obase + (size_t)r * WW) + c;
        __builtin_nontemporal_store(o, op);
#pragma unroll
        for (int k = 0; k < 6; ++k) { up[k] = mid[k]; mid[k] = dn[k]; }
    }
}

extern "C" void kernel_launch(void* const* d_in, const int* in_sizes, int n_in,
                              void* d_out, int out_size, void* d_ws, size_t ws_size,
                              hipStream_t stream) {
    const float* x = (const float*)d_in[0];
    float* out = (float*)d_out;
    // ws layout: [NIMG*NBLK sums][NIMG*NBLK sumsqs][NIMG counters]
    float* partials = (float*)d_ws;
    int* count = (int*)(partials + 2 * NIMG * NBLK);

    ltpe_zero_counts<<<1, NIMG, 0, stream>>>(count);
    ltpe_onepass<<<NIMG * NBLK, TPB, 0, stream>>>(x, partials, count, out);
}

// Round 6
// 70.889 us; speedup vs baseline: 2.7731x; 2.4101x over previous
//
#include <hip/hip_runtime.h>

// LTPE: y(p) = x(p) - sum_j w_j * x(p + off_j), zero-padded borders,
// then instance-norm over HxW per image: (y - mean) * rsqrt(var + 4e-5).
// (The reference's out = 0.5*y + 0.5; instance norm is affine-invariant,
//  with eps folding 1e-5 -> 4e-5.)
//
// Two plain kernels (round-5 showed device-scope barrier/spin fusion costs
// ~130us in L2 invalidate/writeback traffic; the inter-kernel gap is ~2us).
// Each pass: 4-buffer rolling-row pipeline, dn-row load issued 2 iterations
// ahead of use; fully unrolled so all buffer indices are compile-time.

#define HH 1024
#define WW 1024
#define NIMG 32
#define NBLK 32                  // blocks per image
#define RPB (HH / NBLK)          // 32 rows per block
#define TPB 256                  // = WW/4 float4 columns per row

typedef float vfloat4 __attribute__((ext_vector_type(4)));

// weights: j=0..7 -> 2^j/255, offsets (dy,dx):
// j0 (0,-1), j1 (1,-1), j2 (1,0), j3 (1,1), j4 (0,1), j5 (-1,1), j6 (-1,0), j7 (-1,-1)
__device__ __forceinline__ void compute_y(const float* up, const float* mid,
                                          const float* dn, float* y) {
    const float w0 = 1.f / 255.f,  w1 = 2.f / 255.f,  w2 = 4.f / 255.f,
                w3 = 8.f / 255.f,  w4 = 16.f / 255.f, w5 = 32.f / 255.f,
                w6 = 64.f / 255.f, w7 = 128.f / 255.f;
#pragma unroll
    for (int k = 0; k < 4; ++k) {
        float s = w0 * mid[k] + w4 * mid[k + 2]
                + w1 * dn[k]  + w2 * dn[k + 1] + w3 * dn[k + 2]
                + w7 * up[k]  + w6 * up[k + 1] + w5 * up[k + 2];
        y[k] = mid[k + 1] - s;
    }
}

// buf[0]=left halo, buf[1..4]=vfloat4, buf[5]=right halo; zeros out of range
__device__ __forceinline__ void load_row_g(const float* __restrict__ base,
                                           int r, int c, float* buf) {
    if (r < 0 || r >= HH) {
#pragma unroll
        for (int k = 0; k < 6; ++k) buf[k] = 0.f;
        return;
    }
    const float* row = base + (size_t)r * WW;
    const vfloat4 v = reinterpret_cast<const vfloat4*>(row)[c];
    buf[0] = (c > 0) ? row[4 * c - 1] : 0.f;
    buf[1] = v.x; buf[2] = v.y; buf[3] = v.z; buf[4] = v.w;
    buf[5] = (c < TPB - 1) ? row[4 * c + 4] : 0.f;
}

template <bool NORM>
__global__ __launch_bounds__(TPB) void ltpe_pass(const float* __restrict__ x,
                                                 float* __restrict__ partials,
                                                 float* __restrict__ out) {
    const int img = blockIdx.x / NBLK;
    const int blk = blockIdx.x % NBLK;
    const int c = threadIdx.x;
    const float* base = x + (size_t)img * HH * WW;
    const int r0 = blk * RPB;

    float mean = 0.f, scale = 1.f;
    if (NORM) {
        // redundant per-block final reduce of this image's 32 partials
        __shared__ float sh_stats[2];
        if (threadIdx.x < 64) {
            const int lane = threadIdx.x;
            double S = 0.0, SS = 0.0;
            if (lane < NBLK) {
                S = (double)partials[img * NBLK + lane];
                SS = (double)partials[NIMG * NBLK + img * NBLK + lane];
            }
#pragma unroll
            for (int off = 32; off > 0; off >>= 1) {
                S += __shfl_down(S, off);
                SS += __shfl_down(SS, off);
            }
            if (lane == 0) {
                const double N = (double)HH * (double)WW;
                const double m = S / N;
                const double var = SS / N - m * m;
                sh_stats[0] = (float)m;
                sh_stats[1] = (float)(1.0 / sqrt(var + 4e-5)); // 4*eps folds 0.5
            }
        }
        __syncthreads();
        mean = sh_stats[0];
        scale = sh_stats[1];
    }

    // rolling 4-row register pipeline: iter i uses buf[i&3]=row r-1,
    // buf[(i+1)&3]=row r, buf[(i+2)&3]=row r+1; prefetches row r+3 into
    // buf[i&3] (2 iterations ahead of its use as dn).
    float buf[4][6];
    load_row_g(base, r0 - 1, c, buf[0]);
    load_row_g(base, r0,     c, buf[1]);
    load_row_g(base, r0 + 1, c, buf[2]);
    load_row_g(base, r0 + 2, c, buf[3]);

    float s = 0.f, ss = 0.f;
    float* obase = out + (size_t)img * HH * WW;

#pragma unroll
    for (int i = 0; i < RPB; ++i) {
        const int r = r0 + i;
        float y[4];
        compute_y(buf[i & 3], buf[(i + 1) & 3], buf[(i + 2) & 3], y);
        if (NORM) {
            vfloat4 o;
            o.x = (y[0] - mean) * scale;
            o.y = (y[1] - mean) * scale;
            o.z = (y[2] - mean) * scale;
            o.w = (y[3] - mean) * scale;
            // nt: don't let the 128 MB output stream evict x from L3
            __builtin_nontemporal_store(
                o, reinterpret_cast<vfloat4*>(obase + (size_t)r * WW) + c);
        } else {
#pragma unroll
            for (int k = 0; k < 4; ++k) { s += y[k]; ss = fmaf(y[k], y[k], ss); }
        }
        if (i + 2 < RPB)  // row r+3 serves as dn in iter i+2
            load_row_g(base, r + 3, c, buf[i & 3]);
    }

    if (!NORM) {
        // block reduction: wave64 shuffle, then LDS across 4 waves
#pragma unroll
        for (int off = 32; off > 0; off >>= 1) {
            s += __shfl_down(s, off);
            ss += __shfl_down(ss, off);
        }
        __shared__ float sh[8];
        const int wave = threadIdx.x >> 6;
        const int lane = threadIdx.x & 63;
        if (lane == 0) { sh[wave] = s; sh[4 + wave] = ss; }
        __syncthreads();
        if (threadIdx.x == 0) {
            partials[img * NBLK + blk] = sh[0] + sh[1] + sh[2] + sh[3];
            partials[NIMG * NBLK + img * NBLK + blk] = sh[4] + sh[5] + sh[6] + sh[7];
        }
    }
}

extern "C" void kernel_launch(void* const* d_in, const int* in_sizes, int n_in,
                              void* d_out, int out_size, void* d_ws, size_t ws_size,
                              hipStream_t stream) {
    const float* x = (const float*)d_in[0];
    float* out = (float*)d_out;
    float* partials = (float*)d_ws; // [NIMG*NBLK sums][NIMG*NBLK sumsqs]

    ltpe_pass<false><<<NIMG * NBLK, TPB, 0, stream>>>(x, partials, out);
    ltpe_pass<true><<<NIMG * NBLK, TPB, 0, stream>>>(x, partials, out);
}